// Round 9
// baseline (421.796 us; speedup 1.0000x reference)
//
#include <hip/hip_runtime.h>
#include <hip/hip_fp16.h>

// Problem constants
#define NN 50000              // num nodes
#define EE 300000             // edges per type
#define ETOT (3 * EE)         // 900000
#define HD 64                 // hidden / feature size
#define RB 256                // rows per bucket
#define NB 196                // ceil(NN / RB)
#define CHUNK 8192            // edges per binning block
#define NBLKT ((EE + CHUNK - 1) / CHUNK)   // 37 blocks per edge type
#define NBT (3 * NBLKT)       // 111 flat blocks
#define NTOT (NB * NBT)       // 21756 (bucket,block) cells
#define GS_VPT ((NTOT + 1023) / 1024)      // 22 values per scan thread
#define MAXB 6144             // LDS meta capacity per bucket (mean 4592, +22 sigma)

// H layout: __half2 H[n*64+f] = (channel0, channel1), fp16 storage fp32 math
// meta[pos] = col | (etype<<16) | (q14<<18),  q14 = round(val * 16383)

// ---------------------------------------------------------------------------
// CSR build pass 1: per-block LDS histogram over the 196 row buckets.
// No global atomics (round-7's bin_kernel died on 900K atomics / 196 ctrs).
// hist layout: hist[flat * NB + bucket]  (coalesced write per block)
// ---------------------------------------------------------------------------
__global__ void __launch_bounds__(256)
hist1_kernel(const int* __restrict__ ei0, const int* __restrict__ ei1,
             const int* __restrict__ ei2, int* __restrict__ hist) {
    __shared__ int lh[NB];
    int t = blockIdx.y;
    const int* ei = (t == 0) ? ei0 : (t == 1) ? ei1 : ei2;
    int tid = threadIdx.x;
    for (int i = tid; i < NB; i += 256) lh[i] = 0;
    __syncthreads();
    int e0 = blockIdx.x * CHUNK;
    for (int it = 0; it < CHUNK / 256; ++it) {
        int e = e0 + it * 256 + tid;
        if (e < EE) atomicAdd(&lh[ei[e] >> 8], 1);   // LDS atomic only
    }
    __syncthreads();
    int flat = t * NBLKT + blockIdx.x;
    for (int i = tid; i < NB; i += 256) hist[flat * NB + i] = lh[i];
}

// ---------------------------------------------------------------------------
// CSR build pass 2: single-block exclusive scan of NTOT counts in
// bucket-major, block-minor order -> gbase + per-bucket bases bbase[NB+1]
// + rp[NN]=ETOT.  Also computes the 24 softmax filter weights (folded in
// to save a launch; threads 0..7, independent of the scan).
// ---------------------------------------------------------------------------
__global__ void __launch_bounds__(1024)
gscan_kernel(const int* __restrict__ hist, int* __restrict__ gbase,
             int* __restrict__ bbase, int* __restrict__ rp,
             const float* __restrict__ lw0, const float* __restrict__ lw1,
             float* __restrict__ filt) {
    __shared__ int wsum[16];
    int tid = threadIdx.x, lane = tid & 63, wv = tid >> 6;
    if (tid < 8) {   // filt[b][l][c][:] = softmax(layerW[l][c][:])
        int b = tid >> 2, l = (tid >> 1) & 1, c = tid & 1;
        const float* lw = (b == 0 ? lw0 : lw1) + l * 6 + c * 3;
        float a0 = lw[0], a1 = lw[1], a2 = lw[2];
        float m  = fmaxf(a0, fmaxf(a1, a2));
        float e0 = expf(a0 - m), e1 = expf(a1 - m), e2 = expf(a2 - m);
        float s  = e0 + e1 + e2;
        float* o = filt + tid * 3;
        o[0] = e0 / s; o[1] = e1 / s; o[2] = e2 / s;
    }
    int s0 = tid * GS_VPT;
    int local = 0;
    for (int j = 0; j < GS_VPT; ++j) {
        int s = s0 + j;
        if (s < NTOT) {
            int bucket = s / NBT, flat = s - bucket * NBT;
            local += hist[flat * NB + bucket];
        }
    }
    int x = local;
#pragma unroll
    for (int d = 1; d < 64; d <<= 1) {
        int y = __shfl_up(x, d);
        if (lane >= d) x += y;
    }
    if (lane == 63) wsum[wv] = x;
    __syncthreads();
    if (tid == 0) {
        int s = 0;
        for (int i = 0; i < 16; ++i) { int t = wsum[i]; wsum[i] = s; s += t; }
    }
    __syncthreads();
    int run = x + wsum[wv] - local;   // exclusive prefix entering this thread
    for (int j = 0; j < GS_VPT; ++j) {
        int s = s0 + j;
        if (s < NTOT) {
            int bucket = s / NBT, flat = s - bucket * NBT;
            gbase[flat * NB + bucket] = run;
            if (flat == 0) bbase[bucket] = run;
            run += hist[flat * NB + bucket];
        }
    }
    if (tid == 0) { bbase[NB] = ETOT; rp[NN] = ETOT; }
}

// ---------------------------------------------------------------------------
// CSR build pass 3: re-read edges; rank via LDS cursors seeded with exact
// global offsets; write staged in ~336 B contiguous runs per (block,bucket).
// Single-block-sourced lines -> no cross-XCD ping-pong, ~1x write amp.
// ---------------------------------------------------------------------------
__global__ void __launch_bounds__(256)
place_kernel(const int* __restrict__ ei0, const int* __restrict__ ei1,
             const int* __restrict__ ei2,
             const float* __restrict__ ev0, const float* __restrict__ ev1,
             const float* __restrict__ ev2,
             const int* __restrict__ gbase, uint2* __restrict__ staged) {
    __shared__ int lbase[NB];
    int t = blockIdx.y;
    const int*   ei = (t == 0) ? ei0 : (t == 1) ? ei1 : ei2;
    const float* ev = (t == 0) ? ev0 : (t == 1) ? ev1 : ev2;
    int tid = threadIdx.x;
    int flat = t * NBLKT + blockIdx.x;
    for (int i = tid; i < NB; i += 256) lbase[i] = gbase[flat * NB + i];
    __syncthreads();
    int e0 = blockIdx.x * CHUNK;
    for (int it = 0; it < CHUNK / 256; ++it) {
        int e = e0 + it * 256 + tid;
        if (e < EE) {
            int row = ei[e];
            int col = ei[EE + e];
            unsigned int q = (unsigned int)__float2int_rn(ev[e] * 16383.0f);
            unsigned int mw = (unsigned int)col | ((unsigned int)t << 16) | (q << 18);
            int pos = atomicAdd(&lbase[row >> 8], 1);
            staged[pos] = make_uint2(mw, (unsigned int)row);
        }
    }
}

// ---------------------------------------------------------------------------
// CSR build pass 4: one block per bucket. LDS hist over 256 rows -> LDS
// excl scan -> rp writes -> LDS scatter of metawords -> coalesced dump.
// ---------------------------------------------------------------------------
__global__ void __launch_bounds__(256)
csr_kernel(const uint2* __restrict__ staged, const int* __restrict__ bbase,
           int* __restrict__ rp, unsigned int* __restrict__ meta) {
    __shared__ int hist[RB];
    __shared__ int lcur[RB];
    __shared__ int wsum[4];
    __shared__ unsigned int metaL[MAXB];   // 24 KB
    int b   = blockIdx.x;
    int tid = threadIdx.x;
    int base = bbase[b];
    int cnt  = bbase[b + 1] - base;
    int row0 = b * RB;

    hist[tid] = 0;
    __syncthreads();
    for (int i = tid; i < cnt; i += 256) {
        uint2 s = staged[base + i];
        atomicAdd(&hist[(int)s.y - row0], 1);
    }
    __syncthreads();
    int lane = tid & 63, wv = tid >> 6;
    int v = hist[tid];
    int x = v;
#pragma unroll
    for (int d = 1; d < 64; d <<= 1) {
        int y = __shfl_up(x, d);
        if (lane >= d) x += y;
    }
    if (lane == 63) wsum[wv] = x;
    __syncthreads();
    if (tid == 0) {
        int s = 0;
        for (int i = 0; i < 4; ++i) { int t = wsum[i]; wsum[i] = s; s += t; }
    }
    __syncthreads();
    int excl = x + wsum[wv] - v;
    lcur[tid] = excl;
    int row = row0 + tid;
    if (row < NN) rp[row] = base + excl;
    __syncthreads();
    for (int i = tid; i < cnt; i += 256) {
        uint2 s = staged[base + i];
        int p = atomicAdd(&lcur[(int)s.y - row0], 1);
        metaL[p] = s.x;
    }
    __syncthreads();
    for (int i = tid; i < cnt; i += 256)
        meta[base + i] = metaL[i];
}

// ---------------------------------------------------------------------------
// Projection: Hh[n][o] = half2( X@Ws[0], X@Ws[1] )[n][o]
// 16-node tiles; thread = (node, 4 outputs); float4 weight reads broadcast.
// Keep VGPR small (round-4's big tile spilled).
// ---------------------------------------------------------------------------
#define PROJ_NTILE (NN / 16)   // 3125, exact
__global__ void __launch_bounds__(256)
proj_kernel(const float* __restrict__ Xin, const float* __restrict__ Ws,
            __half2* __restrict__ Hh) {
    __shared__ float Wl[2 * 64 * 64];    // 32 KB, [c][f][o]
    __shared__ float Xs[16 * 65];        // padded stride 65
    int tid = threadIdx.x;
    for (int i = tid; i < 2 * 64 * 64; i += 256) Wl[i] = Ws[i];
    int oq = (tid & 15) * 4;    // 4 consecutive outputs
    int ln = tid >> 4;          // node 0..15
    for (int tile = blockIdx.x; tile < PROJ_NTILE; tile += gridDim.x) {
        int n0 = tile * 16;
        __syncthreads();
        for (int i = tid; i < 16 * 64; i += 256)
            Xs[(i >> 6) * 65 + (i & 63)] = Xin[(n0 + (i >> 6)) * 64 + (i & 63)];
        __syncthreads();
        float a0[4] = {0.f, 0.f, 0.f, 0.f};
        float a1[4] = {0.f, 0.f, 0.f, 0.f};
        for (int f = 0; f < 64; ++f) {
            float  x  = Xs[ln * 65 + f];
            float4 w0 = *(const float4*)&Wl[f * 64 + oq];
            float4 w1 = *(const float4*)&Wl[4096 + f * 64 + oq];
            a0[0] += x * w0.x; a0[1] += x * w0.y;
            a0[2] += x * w0.z; a0[3] += x * w0.w;
            a1[0] += x * w1.x; a1[1] += x * w1.y;
            a1[2] += x * w1.z; a1[3] += x * w1.w;
        }
        float4 o4;
        ((__half2*)&o4)[0] = __floats2half2_rn(a0[0], a1[0]);
        ((__half2*)&o4)[1] = __floats2half2_rn(a0[1], a1[1]);
        ((__half2*)&o4)[2] = __floats2half2_rn(a0[2], a1[2]);
        ((__half2*)&o4)[3] = __floats2half2_rn(a0[3], a1[3]);
        *(float4*)&Hh[(n0 + ln) * HD + oq] = o4;
    }
}

// ---------------------------------------------------------------------------
// CSR SpMM-mix, wide-gather: one wave per row; lane = (edge-subslot g,
// feature-quad fq). 16-edge chunks put FOUR independent dwordx4 gathers in
// flight per lane (round-8's 8-edge chunks held only two -> latency-bound).
// Padding lanes carry m=0 -> q=0 -> contribute exactly 0 (no tail logic).
// shfl_xor 16/32 reduction at the end.
// ---------------------------------------------------------------------------
__global__ void __launch_bounds__(256)
spmm_kernel(const float4* __restrict__ Hin4, float4* __restrict__ Hout4,
            const unsigned int* __restrict__ meta, const int* __restrict__ rp,
            const float* __restrict__ filt /* [2][3] for this pass */) {
    const int wid  = threadIdx.x >> 6;
    const int lane = threadIdx.x & 63;
    const int g    = lane >> 4;
    const int fq   = lane & 15;
    const int row  = blockIdx.x * 4 + wid;

    const float s = 1.0f / 16383.0f;
    const float F00 = filt[0] * s, F01 = filt[1] * s, F02 = filt[2] * s;
    const float F10 = filt[3] * s, F11 = filt[4] * s, F12 = filt[5] * s;

    float accA[4] = {0.f, 0.f, 0.f, 0.f};   // ch0
    float accB[4] = {0.f, 0.f, 0.f, 0.f};   // ch1

    const int beg = rp[row], end = rp[row + 1];
    for (int j0 = beg; j0 < end; j0 += 64) {
        int cnt = min(end - j0, 64);
        unsigned int m = (lane < cnt) ? meta[j0 + lane] : 0u;
        for (int k = 0; k < cnt; k += 16) {
            unsigned int mm0 = (unsigned int)__shfl((int)m, k + g);
            unsigned int mm1 = (unsigned int)__shfl((int)m, k + 4 + g);
            unsigned int mm2 = (unsigned int)__shfl((int)m, k + 8 + g);
            unsigned int mm3 = (unsigned int)__shfl((int)m, k + 12 + g);
            float4 r0 = Hin4[(mm0 & 0xffffu) * 16 + fq];
            float4 r1 = Hin4[(mm1 & 0xffffu) * 16 + fq];
            float4 r2 = Hin4[(mm2 & 0xffffu) * 16 + fq];
            float4 r3 = Hin4[(mm3 & 0xffffu) * 16 + fq];
            int   et0 = (mm0 >> 16) & 3, et1 = (mm1 >> 16) & 3;
            int   et2 = (mm2 >> 16) & 3, et3 = (mm3 >> 16) & 3;
            float q0 = (float)(mm0 >> 18), q1 = (float)(mm1 >> 18);
            float q2 = (float)(mm2 >> 18), q3 = (float)(mm3 >> 18);
            float w00 = q0 * ((et0 == 0) ? F00 : (et0 == 1) ? F01 : F02);
            float w10 = q0 * ((et0 == 0) ? F10 : (et0 == 1) ? F11 : F12);
            float w01 = q1 * ((et1 == 0) ? F00 : (et1 == 1) ? F01 : F02);
            float w11 = q1 * ((et1 == 0) ? F10 : (et1 == 1) ? F11 : F12);
            float w02 = q2 * ((et2 == 0) ? F00 : (et2 == 1) ? F01 : F02);
            float w12 = q2 * ((et2 == 0) ? F10 : (et2 == 1) ? F11 : F12);
            float w03 = q3 * ((et3 == 0) ? F00 : (et3 == 1) ? F01 : F02);
            float w13 = q3 * ((et3 == 0) ? F10 : (et3 == 1) ? F11 : F12);
#pragma unroll
            for (int i = 0; i < 4; ++i) {
                float2 x0 = __half22float2(((const __half2*)&r0)[i]);
                float2 x1 = __half22float2(((const __half2*)&r1)[i]);
                float2 x2 = __half22float2(((const __half2*)&r2)[i]);
                float2 x3 = __half22float2(((const __half2*)&r3)[i]);
                accA[i] += w00 * x0.x + w01 * x1.x + w02 * x2.x + w03 * x3.x;
                accB[i] += w10 * x0.y + w11 * x1.y + w12 * x2.y + w13 * x3.y;
            }
        }
    }
#pragma unroll
    for (int i = 0; i < 4; ++i) {
        accA[i] += __shfl_xor(accA[i], 16); accA[i] += __shfl_xor(accA[i], 32);
        accB[i] += __shfl_xor(accB[i], 16); accB[i] += __shfl_xor(accB[i], 32);
    }
    if (g == 0) {
        float4 o4;
        ((__half2*)&o4)[0] = __floats2half2_rn(accA[0], accB[0]);
        ((__half2*)&o4)[1] = __floats2half2_rn(accA[1], accB[1]);
        ((__half2*)&o4)[2] = __floats2half2_rn(accA[2], accB[2]);
        ((__half2*)&o4)[3] = __floats2half2_rn(accA[3], accB[3]);
        Hout4[row * 16 + fq] = o4;
    }
}

// ---------------------------------------------------------------------------
// Epilogue: Hm = 0.8*relu(0.5*X0+0.5*H) + 0.2*X0 per [c][n][d], then
// out[n] = relu(Hm[n,:128] @ linW + linb).  64-node tiles, 4x4 reg tile.
// ---------------------------------------------------------------------------
#define EPI_TILE 64
#define HS_STRIDE 132   // pad: 16B-aligned rows, conflict-spread
__global__ void __launch_bounds__(256)
epilogue_kernel(const __half2* __restrict__ X0, const __half2* __restrict__ H,
                const float* __restrict__ linW, const float* __restrict__ linb,
                float* __restrict__ out) {
    __shared__ float Wl[128 * 64];               // 32 KB
    __shared__ float Hs[EPI_TILE * HS_STRIDE];   // 33.8 KB
    int tid = threadIdx.x;
    for (int i = tid; i < 128 * 64; i += 256) Wl[i] = linW[i];
    int oq = tid & 15, nq = tid >> 4;
    float bias[4];
#pragma unroll
    for (int i = 0; i < 4; ++i) bias[i] = linb[oq + 16 * i];
    const int ntiles = (NN + EPI_TILE - 1) / EPI_TILE;
    for (int tile = blockIdx.x; tile < ntiles; tile += gridDim.x) {
        int n0 = tile * EPI_TILE;
        __syncthreads();
        for (int i = tid; i < EPI_TILE * 64; i += 256) {
            int ln = i >> 6, d = i & 63;
            int n = n0 + ln;
            float2 x0 = make_float2(0.f, 0.f), h = make_float2(0.f, 0.f);
            if (n < NN) {
                x0 = __half22float2(X0[n * HD + d]);
                h  = __half22float2(H [n * HD + d]);
            }
            float z0 = fmaxf(0.5f * x0.x + 0.5f * h.x, 0.f);
            float z1 = fmaxf(0.5f * x0.y + 0.5f * h.y, 0.f);
            Hs[ln * HS_STRIDE + d]      = 0.8f * z0 + 0.2f * x0.x;
            Hs[ln * HS_STRIDE + 64 + d] = 0.8f * z1 + 0.2f * x0.y;
        }
        __syncthreads();
        float acc[4][4];
#pragma unroll
        for (int j = 0; j < 4; ++j)
#pragma unroll
            for (int i = 0; i < 4; ++i) acc[j][i] = bias[i];
        for (int k = 0; k < 128; k += 4) {
            float4 hq[4];
#pragma unroll
            for (int j = 0; j < 4; ++j)
                hq[j] = *(const float4*)&Hs[(nq + 16 * j) * HS_STRIDE + k];
#pragma unroll
            for (int kk = 0; kk < 4; ++kk) {
                float w[4];
#pragma unroll
                for (int i = 0; i < 4; ++i) w[i] = Wl[(k + kk) * 64 + oq + 16 * i];
#pragma unroll
                for (int j = 0; j < 4; ++j) {
                    float x = (kk == 0) ? hq[j].x : (kk == 1) ? hq[j].y
                             : (kk == 2) ? hq[j].z : hq[j].w;
#pragma unroll
                    for (int i = 0; i < 4; ++i) acc[j][i] += x * w[i];
                }
            }
        }
#pragma unroll
        for (int j = 0; j < 4; ++j) {
            int n = n0 + nq + 16 * j;
            if (n < NN) {
#pragma unroll
                for (int i = 0; i < 4; ++i)
                    out[n * HD + oq + 16 * i] = fmaxf(acc[j][i], 0.f);
            }
        }
    }
}

// ---------------------------------------------------------------------------
extern "C" void kernel_launch(void* const* d_in, const int* in_sizes, int n_in,
                              void* d_out, int out_size, void* d_ws, size_t ws_size,
                              hipStream_t stream) {
    const float* X     = (const float*)d_in[0];
    const float* ev0   = (const float*)d_in[1];
    const float* ev1   = (const float*)d_in[2];
    const float* ev2   = (const float*)d_in[3];
    const float* Ws0   = (const float*)d_in[4];
    const float* Ws1   = (const float*)d_in[5];
    const float* lw0   = (const float*)d_in[6];
    const float* lw1   = (const float*)d_in[7];
    const float* linW0 = (const float*)d_in[8];
    const float* linb0 = (const float*)d_in[9];
    const float* linW1 = (const float*)d_in[10];
    const float* linb1 = (const float*)d_in[11];
    const int*   ei0   = (const int*)d_in[12];
    const int*   ei1   = (const int*)d_in[13];
    const int*   ei2   = (const int*)d_in[14];
    float* out = (float*)d_out;

    // Workspace (4-byte units):
    // X0h | Ha | Hb (each NN*HD half2) | mid (NN*HD f32; staged aliases it) |
    // filt(32) | hist(NTOT) | gbase(NTOT) | bbase(NB+1 pad) | rp(NN+1 pad) |
    // meta(ETOT)
    float* ws = (float*)d_ws;
    __half2* X0h = (__half2*)(ws);
    __half2* Ha  = (__half2*)(ws + 1 * NN * HD);
    __half2* Hb  = (__half2*)(ws + 2 * NN * HD);
    float*   mid = ws + 3 * NN * HD;
    uint2*   staged = (uint2*)mid;            // dead before mid is written
    float*   filt   = ws + 4 * NN * HD;
    int*     hist   = (int*)(filt + 32);
    int*     gbase  = hist + NTOT;
    int*     bbase  = gbase + NTOT;
    int*     rp     = bbase + NB + 4;
    unsigned int* meta = (unsigned int*)(rp + NN + 16);

    // ---- filters + atomic-free binned CSR build, once per launch ----
    dim3 egrid(NBLKT, 3);
    hist1_kernel<<<egrid, 256, 0, stream>>>(ei0, ei1, ei2, hist);
    gscan_kernel<<<1, 1024, 0, stream>>>(hist, gbase, bbase, rp,
                                         lw0, lw1, filt);
    place_kernel<<<egrid, 256, 0, stream>>>(ei0, ei1, ei2, ev0, ev1, ev2,
                                            gbase, staged);
    csr_kernel<<<NB, 256, 0, stream>>>(staged, bbase, rp, meta);

    // ---- FastGTN block 0 ----
    proj_kernel<<<512, 256, 0, stream>>>(X, Ws0, X0h);
    spmm_kernel<<<NN / 4, 256, 0, stream>>>((const float4*)X0h, (float4*)Ha,
                                            meta, rp, filt + 0);
    spmm_kernel<<<NN / 4, 256, 0, stream>>>((const float4*)Ha, (float4*)Hb,
                                            meta, rp, filt + 6);
    epilogue_kernel<<<512, 256, 0, stream>>>(X0h, Hb, linW0, linb0, mid);

    // ---- FastGTN block 1 ----
    proj_kernel<<<512, 256, 0, stream>>>(mid, Ws1, X0h);
    spmm_kernel<<<NN / 4, 256, 0, stream>>>((const float4*)X0h, (float4*)Ha,
                                            meta, rp, filt + 12);
    spmm_kernel<<<NN / 4, 256, 0, stream>>>((const float4*)Ha, (float4*)Hb,
                                            meta, rp, filt + 18);
    epilogue_kernel<<<512, 256, 0, stream>>>(X0h, Hb, linW1, linb1, out);
}

// Round 10
// 392.767 us; speedup vs baseline: 1.0739x; 1.0739x over previous
//
#include <hip/hip_runtime.h>
#include <hip/hip_fp16.h>

// Problem constants
#define NN 50000              // num nodes
#define EE 300000             // edges per type
#define ETOT (3 * EE)         // 900000
#define HD 64                 // hidden / feature size
#define RB 256                // rows per bucket
#define NB 196                // ceil(NN / RB)
#define CHUNK 8192            // edges per binning block
#define NBLKT ((EE + CHUNK - 1) / CHUNK)   // 37 blocks per edge type
#define NBT (3 * NBLKT)       // 111 flat blocks
#define NTOT (NB * NBT)       // 21756 (bucket,block) cells
#define GS_VPT ((NTOT + 1023) / 1024)      // 22 values per scan thread
#define MAXB 6144             // LDS meta capacity per bucket (mean 4592, +22 sigma)
#define PROJ_NTILE (NN / 16)  // 3125 16-node tiles
#define PP_GRID (NBT + 512)   // place(111) + proj(512) fused grid

// H layout: __half2 H[n*64+f] = (channel0, channel1), fp16 storage fp32 math
// meta[pos] = col | (etype<<16) | (q14<<18),  q14 = round(val * 16383)

// ---------------------------------------------------------------------------
// CSR build pass 1: per-block LDS histogram over the 196 row buckets.
// hist layout: hist[flat * NB + bucket]  (coalesced write per block)
// ---------------------------------------------------------------------------
__global__ void __launch_bounds__(256)
hist1_kernel(const int* __restrict__ ei0, const int* __restrict__ ei1,
             const int* __restrict__ ei2, int* __restrict__ hist) {
    __shared__ int lh[NB];
    int t = blockIdx.y;
    const int* ei = (t == 0) ? ei0 : (t == 1) ? ei1 : ei2;
    int tid = threadIdx.x;
    for (int i = tid; i < NB; i += 256) lh[i] = 0;
    __syncthreads();
    int e0 = blockIdx.x * CHUNK;
    for (int it = 0; it < CHUNK / 256; ++it) {
        int e = e0 + it * 256 + tid;
        if (e < EE) atomicAdd(&lh[ei[e] >> 8], 1);   // LDS atomic only
    }
    __syncthreads();
    int flat = t * NBLKT + blockIdx.x;
    for (int i = tid; i < NB; i += 256) hist[flat * NB + i] = lh[i];
}

// ---------------------------------------------------------------------------
// CSR build pass 2: single-block exclusive scan of NTOT counts in
// bucket-major, block-minor order -> gbase + bbase[NB+1] + rp[NN]=ETOT.
// Also computes the 24 softmax filter weights (threads 0..7).
// ---------------------------------------------------------------------------
__global__ void __launch_bounds__(1024)
gscan_kernel(const int* __restrict__ hist, int* __restrict__ gbase,
             int* __restrict__ bbase, int* __restrict__ rp,
             const float* __restrict__ lw0, const float* __restrict__ lw1,
             float* __restrict__ filt) {
    __shared__ int wsum[16];
    int tid = threadIdx.x, lane = tid & 63, wv = tid >> 6;
    if (tid < 8) {   // filt[b][l][c][:] = softmax(layerW[l][c][:])
        int b = tid >> 2, l = (tid >> 1) & 1, c = tid & 1;
        const float* lw = (b == 0 ? lw0 : lw1) + l * 6 + c * 3;
        float a0 = lw[0], a1 = lw[1], a2 = lw[2];
        float m  = fmaxf(a0, fmaxf(a1, a2));
        float e0 = expf(a0 - m), e1 = expf(a1 - m), e2 = expf(a2 - m);
        float s  = e0 + e1 + e2;
        float* o = filt + tid * 3;
        o[0] = e0 / s; o[1] = e1 / s; o[2] = e2 / s;
    }
    int s0 = tid * GS_VPT;
    int local = 0;
    for (int j = 0; j < GS_VPT; ++j) {
        int s = s0 + j;
        if (s < NTOT) {
            int bucket = s / NBT, flat = s - bucket * NBT;
            local += hist[flat * NB + bucket];
        }
    }
    int x = local;
#pragma unroll
    for (int d = 1; d < 64; d <<= 1) {
        int y = __shfl_up(x, d);
        if (lane >= d) x += y;
    }
    if (lane == 63) wsum[wv] = x;
    __syncthreads();
    if (tid == 0) {
        int s = 0;
        for (int i = 0; i < 16; ++i) { int t = wsum[i]; wsum[i] = s; s += t; }
    }
    __syncthreads();
    int run = x + wsum[wv] - local;   // exclusive prefix entering this thread
    for (int j = 0; j < GS_VPT; ++j) {
        int s = s0 + j;
        if (s < NTOT) {
            int bucket = s / NBT, flat = s - bucket * NBT;
            gbase[flat * NB + bucket] = run;
            if (flat == 0) bbase[bucket] = run;
            run += hist[flat * NB + bucket];
        }
    }
    if (tid == 0) { bbase[NB] = ETOT; rp[NN] = ETOT; }
}

// ---------------------------------------------------------------------------
// Fused CSR pass 3 + block-0 projection. The two are independent; fusing
// them overlaps proj behind the CSR chain instead of serializing on the
// stream. Blocks [0, NBT): place edges into staged runs. Blocks [NBT, ...):
// proj tiles. Whole blocks take one path; __syncthreads stays uniform.
// ---------------------------------------------------------------------------
__global__ void __launch_bounds__(256)
place_proj_kernel(const int* __restrict__ ei0, const int* __restrict__ ei1,
                  const int* __restrict__ ei2,
                  const float* __restrict__ ev0, const float* __restrict__ ev1,
                  const float* __restrict__ ev2,
                  const int* __restrict__ gbase, uint2* __restrict__ staged,
                  const float* __restrict__ Xin, const float* __restrict__ Ws,
                  __half2* __restrict__ Hh) {
    __shared__ float Wl[2 * 64 * 64];    // 32 KB (proj)
    __shared__ float Xs[16 * 65];        // 4.2 KB (proj)
    __shared__ int   lbase[NB];          // 784 B (place)
    int tid = threadIdx.x;

    if (blockIdx.x < NBT) {
        // ---------------- place ----------------
        int flat = blockIdx.x;
        int t  = flat / NBLKT;
        int bx = flat - t * NBLKT;
        const int*   ei = (t == 0) ? ei0 : (t == 1) ? ei1 : ei2;
        const float* ev = (t == 0) ? ev0 : (t == 1) ? ev1 : ev2;
        for (int i = tid; i < NB; i += 256) lbase[i] = gbase[flat * NB + i];
        __syncthreads();
        int e0 = bx * CHUNK;
        for (int it = 0; it < CHUNK / 256; ++it) {
            int e = e0 + it * 256 + tid;
            if (e < EE) {
                int row = ei[e];
                int col = ei[EE + e];
                unsigned int q = (unsigned int)__float2int_rn(ev[e] * 16383.0f);
                unsigned int mw = (unsigned int)col | ((unsigned int)t << 16) | (q << 18);
                int pos = atomicAdd(&lbase[row >> 8], 1);
                staged[pos] = make_uint2(mw, (unsigned int)row);
            }
        }
    } else {
        // ---------------- proj (block 0) ----------------
        for (int i = tid; i < 2 * 64 * 64; i += 256) Wl[i] = Ws[i];
        int oq = (tid & 15) * 4;    // 4 consecutive outputs
        int ln = tid >> 4;          // node 0..15
        for (int tile = blockIdx.x - NBT; tile < PROJ_NTILE; tile += 512) {
            int n0 = tile * 16;
            __syncthreads();
            for (int i = tid; i < 16 * 64; i += 256)
                Xs[(i >> 6) * 65 + (i & 63)] = Xin[(n0 + (i >> 6)) * 64 + (i & 63)];
            __syncthreads();
            float a0[4] = {0.f, 0.f, 0.f, 0.f};
            float a1[4] = {0.f, 0.f, 0.f, 0.f};
            for (int f = 0; f < 64; ++f) {
                float  x  = Xs[ln * 65 + f];
                float4 w0 = *(const float4*)&Wl[f * 64 + oq];
                float4 w1 = *(const float4*)&Wl[4096 + f * 64 + oq];
                a0[0] += x * w0.x; a0[1] += x * w0.y;
                a0[2] += x * w0.z; a0[3] += x * w0.w;
                a1[0] += x * w1.x; a1[1] += x * w1.y;
                a1[2] += x * w1.z; a1[3] += x * w1.w;
            }
            float4 o4;
            ((__half2*)&o4)[0] = __floats2half2_rn(a0[0], a1[0]);
            ((__half2*)&o4)[1] = __floats2half2_rn(a0[1], a1[1]);
            ((__half2*)&o4)[2] = __floats2half2_rn(a0[2], a1[2]);
            ((__half2*)&o4)[3] = __floats2half2_rn(a0[3], a1[3]);
            *(float4*)&Hh[(n0 + ln) * HD + oq] = o4;
        }
    }
}

// ---------------------------------------------------------------------------
// CSR build pass 4: one block per bucket. LDS hist over 256 rows -> LDS
// excl scan -> rp writes -> LDS scatter of metawords -> coalesced dump.
// ---------------------------------------------------------------------------
__global__ void __launch_bounds__(256)
csr_kernel(const uint2* __restrict__ staged, const int* __restrict__ bbase,
           int* __restrict__ rp, unsigned int* __restrict__ meta) {
    __shared__ int hist[RB];
    __shared__ int lcur[RB];
    __shared__ int wsum[4];
    __shared__ unsigned int metaL[MAXB];   // 24 KB
    int b   = blockIdx.x;
    int tid = threadIdx.x;
    int base = bbase[b];
    int cnt  = bbase[b + 1] - base;
    int row0 = b * RB;

    hist[tid] = 0;
    __syncthreads();
    for (int i = tid; i < cnt; i += 256) {
        uint2 s = staged[base + i];
        atomicAdd(&hist[(int)s.y - row0], 1);
    }
    __syncthreads();
    int lane = tid & 63, wv = tid >> 6;
    int v = hist[tid];
    int x = v;
#pragma unroll
    for (int d = 1; d < 64; d <<= 1) {
        int y = __shfl_up(x, d);
        if (lane >= d) x += y;
    }
    if (lane == 63) wsum[wv] = x;
    __syncthreads();
    if (tid == 0) {
        int s = 0;
        for (int i = 0; i < 4; ++i) { int t = wsum[i]; wsum[i] = s; s += t; }
    }
    __syncthreads();
    int excl = x + wsum[wv] - v;
    lcur[tid] = excl;
    int row = row0 + tid;
    if (row < NN) rp[row] = base + excl;
    __syncthreads();
    for (int i = tid; i < cnt; i += 256) {
        uint2 s = staged[base + i];
        int p = atomicAdd(&lcur[(int)s.y - row0], 1);
        metaL[p] = s.x;
    }
    __syncthreads();
    for (int i = tid; i < cnt; i += 256)
        meta[base + i] = metaL[i];
}

// ---------------------------------------------------------------------------
// Projection (standalone, for block 1): Hh[n][o] = half2(X@Ws[0], X@Ws[1])
// ---------------------------------------------------------------------------
__global__ void __launch_bounds__(256)
proj_kernel(const float* __restrict__ Xin, const float* __restrict__ Ws,
            __half2* __restrict__ Hh) {
    __shared__ float Wl[2 * 64 * 64];    // 32 KB, [c][f][o]
    __shared__ float Xs[16 * 65];        // padded stride 65
    int tid = threadIdx.x;
    for (int i = tid; i < 2 * 64 * 64; i += 256) Wl[i] = Ws[i];
    int oq = (tid & 15) * 4;    // 4 consecutive outputs
    int ln = tid >> 4;          // node 0..15
    for (int tile = blockIdx.x; tile < PROJ_NTILE; tile += gridDim.x) {
        int n0 = tile * 16;
        __syncthreads();
        for (int i = tid; i < 16 * 64; i += 256)
            Xs[(i >> 6) * 65 + (i & 63)] = Xin[(n0 + (i >> 6)) * 64 + (i & 63)];
        __syncthreads();
        float a0[4] = {0.f, 0.f, 0.f, 0.f};
        float a1[4] = {0.f, 0.f, 0.f, 0.f};
        for (int f = 0; f < 64; ++f) {
            float  x  = Xs[ln * 65 + f];
            float4 w0 = *(const float4*)&Wl[f * 64 + oq];
            float4 w1 = *(const float4*)&Wl[4096 + f * 64 + oq];
            a0[0] += x * w0.x; a0[1] += x * w0.y;
            a0[2] += x * w0.z; a0[3] += x * w0.w;
            a1[0] += x * w1.x; a1[1] += x * w1.y;
            a1[2] += x * w1.z; a1[3] += x * w1.w;
        }
        float4 o4;
        ((__half2*)&o4)[0] = __floats2half2_rn(a0[0], a1[0]);
        ((__half2*)&o4)[1] = __floats2half2_rn(a0[1], a1[1]);
        ((__half2*)&o4)[2] = __floats2half2_rn(a0[2], a1[2]);
        ((__half2*)&o4)[3] = __floats2half2_rn(a0[3], a1[3]);
        *(float4*)&Hh[(n0 + ln) * HD + oq] = o4;
    }
}

// ---------------------------------------------------------------------------
// CSR SpMM-mix, wide-gather (8-edge chunks — measured best; 16-edge chunks
// regressed from padding-slot gathers): one wave per row; lane =
// (edge-subslot g, feature-quad fq); one dwordx4 per lane per 4 edges;
// shfl_xor 16/32 reduction.
// ---------------------------------------------------------------------------
__global__ void __launch_bounds__(256)
spmm_kernel(const float4* __restrict__ Hin4, float4* __restrict__ Hout4,
            const unsigned int* __restrict__ meta, const int* __restrict__ rp,
            const float* __restrict__ filt /* [2][3] for this pass */) {
    const int wid  = threadIdx.x >> 6;
    const int lane = threadIdx.x & 63;
    const int g    = lane >> 4;
    const int fq   = lane & 15;
    const int row  = blockIdx.x * 4 + wid;

    const float s = 1.0f / 16383.0f;
    const float F00 = filt[0] * s, F01 = filt[1] * s, F02 = filt[2] * s;
    const float F10 = filt[3] * s, F11 = filt[4] * s, F12 = filt[5] * s;

    float accA[4] = {0.f, 0.f, 0.f, 0.f};   // ch0
    float accB[4] = {0.f, 0.f, 0.f, 0.f};   // ch1

    const int beg = rp[row], end = rp[row + 1];
    for (int j0 = beg; j0 < end; j0 += 64) {
        int cnt = min(end - j0, 64);
        unsigned int m = (lane < cnt) ? meta[j0 + lane] : 0u;
        for (int k = 0; k < cnt; k += 8) {
            unsigned int mmA = (unsigned int)__shfl((int)m, k + g);
            unsigned int mmB = (unsigned int)__shfl((int)m, k + 4 + g);
            float4 rA = Hin4[(mmA & 0xffffu) * 16 + fq];
            float4 rB = Hin4[(mmB & 0xffffu) * 16 + fq];
            int   etA = (mmA >> 16) & 3,  etB = (mmB >> 16) & 3;
            float qA  = (float)(mmA >> 18), qB = (float)(mmB >> 18);
            float w0A = qA * ((etA == 0) ? F00 : (etA == 1) ? F01 : F02);
            float w1A = qA * ((etA == 0) ? F10 : (etA == 1) ? F11 : F12);
            float w0B = qB * ((etB == 0) ? F00 : (etB == 1) ? F01 : F02);
            float w1B = qB * ((etB == 0) ? F10 : (etB == 1) ? F11 : F12);
#pragma unroll
            for (int i = 0; i < 4; ++i) {
                float2 xA = __half22float2(((const __half2*)&rA)[i]);
                float2 xB = __half22float2(((const __half2*)&rB)[i]);
                accA[i] += w0A * xA.x + w0B * xB.x;
                accB[i] += w1A * xA.y + w1B * xB.y;
            }
        }
    }
#pragma unroll
    for (int i = 0; i < 4; ++i) {
        accA[i] += __shfl_xor(accA[i], 16); accA[i] += __shfl_xor(accA[i], 32);
        accB[i] += __shfl_xor(accB[i], 16); accB[i] += __shfl_xor(accB[i], 32);
    }
    if (g == 0) {
        float4 o4;
        ((__half2*)&o4)[0] = __floats2half2_rn(accA[0], accB[0]);
        ((__half2*)&o4)[1] = __floats2half2_rn(accA[1], accB[1]);
        ((__half2*)&o4)[2] = __floats2half2_rn(accA[2], accB[2]);
        ((__half2*)&o4)[3] = __floats2half2_rn(accA[3], accB[3]);
        Hout4[row * 16 + fq] = o4;
    }
}

// ---------------------------------------------------------------------------
// Epilogue: Hm = 0.8*relu(0.5*X0+0.5*H) + 0.2*X0 per [c][n][d], then
// out[n] = relu(Hm[n,:128] @ linW + linb).  64-node tiles, 4x4 reg tile.
// ---------------------------------------------------------------------------
#define EPI_TILE 64
#define HS_STRIDE 132   // pad: 16B-aligned rows, conflict-spread
__global__ void __launch_bounds__(256)
epilogue_kernel(const __half2* __restrict__ X0, const __half2* __restrict__ H,
                const float* __restrict__ linW, const float* __restrict__ linb,
                float* __restrict__ out) {
    __shared__ float Wl[128 * 64];               // 32 KB
    __shared__ float Hs[EPI_TILE * HS_STRIDE];   // 33.8 KB
    int tid = threadIdx.x;
    for (int i = tid; i < 128 * 64; i += 256) Wl[i] = linW[i];
    int oq = tid & 15, nq = tid >> 4;
    float bias[4];
#pragma unroll
    for (int i = 0; i < 4; ++i) bias[i] = linb[oq + 16 * i];
    const int ntiles = (NN + EPI_TILE - 1) / EPI_TILE;
    for (int tile = blockIdx.x; tile < ntiles; tile += gridDim.x) {
        int n0 = tile * EPI_TILE;
        __syncthreads();
        for (int i = tid; i < EPI_TILE * 64; i += 256) {
            int ln = i >> 6, d = i & 63;
            int n = n0 + ln;
            float2 x0 = make_float2(0.f, 0.f), h = make_float2(0.f, 0.f);
            if (n < NN) {
                x0 = __half22float2(X0[n * HD + d]);
                h  = __half22float2(H [n * HD + d]);
            }
            float z0 = fmaxf(0.5f * x0.x + 0.5f * h.x, 0.f);
            float z1 = fmaxf(0.5f * x0.y + 0.5f * h.y, 0.f);
            Hs[ln * HS_STRIDE + d]      = 0.8f * z0 + 0.2f * x0.x;
            Hs[ln * HS_STRIDE + 64 + d] = 0.8f * z1 + 0.2f * x0.y;
        }
        __syncthreads();
        float acc[4][4];
#pragma unroll
        for (int j = 0; j < 4; ++j)
#pragma unroll
            for (int i = 0; i < 4; ++i) acc[j][i] = bias[i];
        for (int k = 0; k < 128; k += 4) {
            float4 hq[4];
#pragma unroll
            for (int j = 0; j < 4; ++j)
                hq[j] = *(const float4*)&Hs[(nq + 16 * j) * HS_STRIDE + k];
#pragma unroll
            for (int kk = 0; kk < 4; ++kk) {
                float w[4];
#pragma unroll
                for (int i = 0; i < 4; ++i) w[i] = Wl[(k + kk) * 64 + oq + 16 * i];
#pragma unroll
                for (int j = 0; j < 4; ++j) {
                    float x = (kk == 0) ? hq[j].x : (kk == 1) ? hq[j].y
                             : (kk == 2) ? hq[j].z : hq[j].w;
#pragma unroll
                    for (int i = 0; i < 4; ++i) acc[j][i] += x * w[i];
                }
            }
        }
#pragma unroll
        for (int j = 0; j < 4; ++j) {
            int n = n0 + nq + 16 * j;
            if (n < NN) {
#pragma unroll
                for (int i = 0; i < 4; ++i)
                    out[n * HD + oq + 16 * i] = fmaxf(acc[j][i], 0.f);
            }
        }
    }
}

// ---------------------------------------------------------------------------
extern "C" void kernel_launch(void* const* d_in, const int* in_sizes, int n_in,
                              void* d_out, int out_size, void* d_ws, size_t ws_size,
                              hipStream_t stream) {
    const float* X     = (const float*)d_in[0];
    const float* ev0   = (const float*)d_in[1];
    const float* ev1   = (const float*)d_in[2];
    const float* ev2   = (const float*)d_in[3];
    const float* Ws0   = (const float*)d_in[4];
    const float* Ws1   = (const float*)d_in[5];
    const float* lw0   = (const float*)d_in[6];
    const float* lw1   = (const float*)d_in[7];
    const float* linW0 = (const float*)d_in[8];
    const float* linb0 = (const float*)d_in[9];
    const float* linW1 = (const float*)d_in[10];
    const float* linb1 = (const float*)d_in[11];
    const int*   ei0   = (const int*)d_in[12];
    const int*   ei1   = (const int*)d_in[13];
    const int*   ei2   = (const int*)d_in[14];
    float* out = (float*)d_out;

    // Workspace (4-byte units):
    // X0h | Ha | Hb (each NN*HD half2) | mid (NN*HD f32; staged aliases it) |
    // filt(32) | hist(NTOT) | gbase(NTOT) | bbase(NB+1 pad) | rp(NN+1 pad) |
    // meta(ETOT)
    float* ws = (float*)d_ws;
    __half2* X0h = (__half2*)(ws);
    __half2* Ha  = (__half2*)(ws + 1 * NN * HD);
    __half2* Hb  = (__half2*)(ws + 2 * NN * HD);
    float*   mid = ws + 3 * NN * HD;
    uint2*   staged = (uint2*)mid;            // dead before mid is written
    float*   filt   = ws + 4 * NN * HD;
    int*     hist   = (int*)(filt + 32);
    int*     gbase  = hist + NTOT;
    int*     bbase  = gbase + NTOT;
    int*     rp     = bbase + NB + 4;
    unsigned int* meta = (unsigned int*)(rp + NN + 16);

    // ---- filters + atomic-free binned CSR build; proj0 overlapped ----
    dim3 egrid(NBLKT, 3);
    hist1_kernel<<<egrid, 256, 0, stream>>>(ei0, ei1, ei2, hist);
    gscan_kernel<<<1, 1024, 0, stream>>>(hist, gbase, bbase, rp,
                                         lw0, lw1, filt);
    place_proj_kernel<<<PP_GRID, 256, 0, stream>>>(ei0, ei1, ei2,
                                                   ev0, ev1, ev2,
                                                   gbase, staged,
                                                   X, Ws0, X0h);
    csr_kernel<<<NB, 256, 0, stream>>>(staged, bbase, rp, meta);

    // ---- FastGTN block 0 ----
    spmm_kernel<<<NN / 4, 256, 0, stream>>>((const float4*)X0h, (float4*)Ha,
                                            meta, rp, filt + 0);
    spmm_kernel<<<NN / 4, 256, 0, stream>>>((const float4*)Ha, (float4*)Hb,
                                            meta, rp, filt + 6);
    epilogue_kernel<<<512, 256, 0, stream>>>(X0h, Hb, linW0, linb0, mid);

    // ---- FastGTN block 1 ----
    proj_kernel<<<512, 256, 0, stream>>>(mid, Ws1, X0h);
    spmm_kernel<<<NN / 4, 256, 0, stream>>>((const float4*)X0h, (float4*)Ha,
                                            meta, rp, filt + 12);
    spmm_kernel<<<NN / 4, 256, 0, stream>>>((const float4*)Ha, (float4*)Hb,
                                            meta, rp, filt + 18);
    epilogue_kernel<<<512, 256, 0, stream>>>(X0h, Hb, linW1, linb1, out);
}